// Round 3
// baseline (642.937 us; speedup 1.0000x reference)
//
#include <hip/hip_runtime.h>
#include <hip/hip_bf16.h>

typedef __bf16 bf16x8 __attribute__((ext_vector_type(8)));
typedef float  f32x4  __attribute__((ext_vector_type(4)));

#define T_   3
#define N_   200000
#define C_   256
#define B_   512
#define CAP  65536
#define EPSb 1e-5f

__device__ __forceinline__ unsigned enc_f(float f){
  unsigned u = __float_as_uint(f);
  return (u & 0x80000000u) ? ~u : (u | 0x80000000u);
}
__device__ __forceinline__ float dec_f(unsigned k){
  unsigned u = (k & 0x80000000u) ? (k ^ 0x80000000u) : ~k;
  return __uint_as_float(u);
}

// raw barrier WITHOUT vmcnt drain (lets prefetch global loads stay in flight)
__device__ __forceinline__ void barrier_nodrain(){
  __builtin_amdgcn_sched_barrier(0);
  asm volatile("s_waitcnt lgkmcnt(0)" ::: "memory");
  __builtin_amdgcn_s_barrier();
  __builtin_amdgcn_sched_barrier(0);
}

// ---------------- prep: Wl transpose->bf16, cvec, zero-fill (one kernel)
__global__ void kprep(const float* __restrict__ Wl, __hip_bfloat16* __restrict__ wlt,
                      const float* __restrict__ Wr, const float* __restrict__ bl,
                      const float* __restrict__ br, const float* __restrict__ gtok,
                      float* __restrict__ cvec, float* __restrict__ zr){
  __shared__ float tile[64][65];
  __shared__ float gt[256];
  int blk = blockIdx.x, tid = threadIdx.x;
  if (blk < 48){
    int t = blk / 16, rem = blk % 16;
    int k0 = (rem >> 2)*64, c0 = (rem & 3)*64;
    int lc = tid & 63, lr0 = tid >> 6;
    #pragma unroll
    for (int q = 0; q < 16; q++){
      int lr = lr0*16 + q;
      tile[lr][lc] = Wl[t*65536 + (k0+lr)*256 + (c0+lc)];
    }
    __syncthreads();
    #pragma unroll
    for (int q = 0; q < 16; q++){
      int lr = lr0*16 + q;
      wlt[t*65536 + (c0+lr)*256 + (k0+lc)] = __float2bfloat16(tile[lc][lr]);
    }
  } else if (blk < 51){
    int t = blk - 48, c = tid;
    gt[tid] = gtok[t*256 + tid];
    __syncthreads();
    const float* wr = Wr + t*65536 + c;
    float a0=0.f,a1=0.f,a2=0.f,a3=0.f;
    #pragma unroll 2
    for (int k = 0; k < 256; k += 4){
      a0 += gt[k]  *wr[k*256];
      a1 += gt[k+1]*wr[(k+1)*256];
      a2 += gt[k+2]*wr[(k+2)*256];
      a3 += gt[k+3]*wr[(k+3)*256];
    }
    cvec[t*256 + c] = a0+a1+a2+a3 + bl[t*256+c] + br[t*256+c];
  } else {
    // zero region: gacc + den + mkey + mexkey + bns + cnt = 399888 floats
    for (int i = (blk-51)*256 + tid; i < 399888; i += (gridDim.x-51)*256) zr[i] = 0.f;
  }
}

// ---------------- big pass: e_approx = att . lrelu(x@Wl + cvec), bf16 MFMA
__global__ __launch_bounds__(512, 2)
void k1(const float* __restrict__ x, const __hip_bfloat16* __restrict__ wlt,
        const float* __restrict__ cvec, const float* __restrict__ att,
        const int* __restrict__ batch, float* __restrict__ e_out,
        unsigned* __restrict__ mkey){
  __shared__ __align__(16) __hip_bfloat16 Abuf[64][256];
  __shared__ float elds[4][64];
  const int t   = blockIdx.y;
  const int tid = threadIdx.x;
  const int w = tid >> 6, l = tid & 63;
  const int wcol = w & 3, wrow = w >> 2;
  const int l15 = l & 15, l4 = l >> 4;

  bf16x8 bfr[8][4];
  float cv[4], at[4];
  const __hip_bfloat16* WT = wlt + t*65536;
  #pragma unroll
  for (int fn = 0; fn < 4; fn++){
    int col = wcol*64 + fn*16 + l15;
    cv[fn] = cvec[t*256 + col];
    at[fn] = att[t*256 + col];
    #pragma unroll
    for (int ks = 0; ks < 8; ks++)
      bfr[ks][fn] = *(const bf16x8*)(WT + col*256 + ks*32 + l4*8);
  }

  const int srow = tid >> 3;
  const int sc   = tid & 7;
  const int sx   = srow & 7;
  const size_t xbase = (size_t)t * N_ * 256;
  const int tile0 = blockIdx.x * 5;

  f32x4 rg[8];
  {
    const float* xrow = x + xbase + (size_t)(tile0*64 + srow)*256;
    #pragma unroll
    for (int q = 0; q < 4; q++){
      int cs = (q*8 + sc) ^ sx;
      rg[2*q]   = *(const f32x4*)(xrow + cs*8);
      rg[2*q+1] = *(const f32x4*)(xrow + cs*8 + 4);
    }
  }

  for (int i = 0; i < 5; i++){
    const int tile = tile0 + i;
    #pragma unroll
    for (int q = 0; q < 4; q++){
      bf16x8 v;
      #pragma unroll
      for (int j = 0; j < 4; j++){ v[j] = (__bf16)rg[2*q][j]; v[4+j] = (__bf16)rg[2*q+1][j]; }
      *(bf16x8*)(&Abuf[srow][(q*8 + sc)*8]) = v;
    }
    if (i < 4){
      const float* xrow = x + xbase + (size_t)((tile+1)*64 + srow)*256;
      #pragma unroll
      for (int q = 0; q < 4; q++){
        int cs = (q*8 + sc) ^ sx;
        rg[2*q]   = *(const f32x4*)(xrow + cs*8);
        rg[2*q+1] = *(const f32x4*)(xrow + cs*8 + 4);
      }
    }
    barrier_nodrain();

    f32x4 acc[2][4];
    #pragma unroll
    for (int fm = 0; fm < 2; fm++)
      #pragma unroll
      for (int fn = 0; fn < 4; fn++)
        acc[fm][fn] = (f32x4){0.f,0.f,0.f,0.f};

    #pragma unroll
    for (int ks = 0; ks < 8; ks++){
      bf16x8 a8[2];
      #pragma unroll
      for (int fm = 0; fm < 2; fm++){
        int row  = wrow*32 + fm*16 + l15;
        int slot = (ks*4 + l4) ^ (row & 7);
        a8[fm] = *(const bf16x8*)(&Abuf[row][slot*8]);
      }
      #pragma unroll
      for (int fm = 0; fm < 2; fm++)
        #pragma unroll
        for (int fn = 0; fn < 4; fn++)
          acc[fm][fn] = __builtin_amdgcn_mfma_f32_16x16x32_bf16(a8[fm], bfr[ks][fn], acc[fm][fn], 0, 0, 0);
    }

    #pragma unroll
    for (int fm = 0; fm < 2; fm++){
      #pragma unroll
      for (int r = 0; r < 4; r++){
        float v = 0.f;
        #pragma unroll
        for (int fn = 0; fn < 4; fn++){
          float xv = acc[fm][fn][r] + cv[fn];
          xv = (xv > 0.f) ? xv : 0.2f*xv;
          v += xv * at[fn];
        }
        v += __shfl_xor(v, 1);
        v += __shfl_xor(v, 2);
        v += __shfl_xor(v, 4);
        v += __shfl_xor(v, 8);
        if (l15 == 0) elds[wcol][wrow*32 + fm*16 + l4*4 + r] = v;
      }
    }
    barrier_nodrain();

    if (tid < 64){
      float ef = elds[0][tid] + elds[1][tid] + elds[2][tid] + elds[3][tid];
      int n = tile*64 + tid;
      e_out[t*N_ + n] = ef;
      int b = batch[t*N_ + n];
      float m = ef;
      #pragma unroll
      for (int off = 1; off < 64; off <<= 1){
        float up = __shfl_up(m, off);
        int   bu = __shfl_up(b, off);
        if (tid >= off && bu == b) m = fmaxf(m, up);
      }
      int bnx = __shfl_down(b, 1);
      if (tid == 63 || b != bnx) atomicMax(&mkey[t*B_ + b], enc_f(m));
    }
  }
}

// ---------------- candidate selection: e >= segmax - 30
__global__ void kselect(const float* __restrict__ e, const int* __restrict__ batch,
                        const unsigned* __restrict__ mkey, int* cnt, int* list){
  int t = blockIdx.y;
  int n = blockIdx.x*256 + threadIdx.x;
  if (n >= N_) return;
  float ev = e[t*N_ + n];
  int b = batch[t*N_ + n];
  float m = dec_f(mkey[t*B_ + b]);
  if (ev >= m - 30.0f){
    int pos = atomicAdd(&cnt[t], 1);
    if (pos < CAP) list[t*CAP + pos] = n;
  }
}

// ---------------- exact fp32 e for candidates
__global__ void kexact(const float* __restrict__ x, const float* __restrict__ Wl,
                       const float* __restrict__ cvec, const float* __restrict__ att,
                       const int* __restrict__ batch, const int* __restrict__ cnt,
                       const int* __restrict__ list, float* __restrict__ eex,
                       unsigned* __restrict__ mexkey){
  __shared__ float xs[256];
  __shared__ float red[4];
  int t = blockIdx.y;
  int c = threadIdx.x;
  int nc = min(cnt[t], CAP);
  for (int ci = blockIdx.x; ci < nc; ci += gridDim.x){
    int n = list[t*CAP + ci];
    xs[c] = x[(size_t)t*N_*256 + (size_t)n*256 + c];
    __syncthreads();
    const float* wp = Wl + t*65536 + c;
    float a0 = 0.f, a1 = 0.f;
    #pragma unroll 8
    for (int k = 0; k < 256; k += 2){
      a0 += xs[k]   * wp[k*256];
      a1 += xs[k+1] * wp[(k+1)*256];
    }
    float xv = a0 + a1 + cvec[t*256 + c];
    xv = (xv > 0.f) ? xv : 0.2f*xv;
    float term = xv * att[t*256 + c];
    #pragma unroll
    for (int off = 1; off < 64; off <<= 1) term += __shfl_xor(term, off);
    if ((c & 63) == 0) red[c >> 6] = term;
    __syncthreads();
    if (c == 0){
      float ev = red[0] + red[1] + red[2] + red[3];
      eex[t*CAP + ci] = ev;
      atomicMax(&mexkey[t*B_ + batch[t*N_ + n]], enc_f(ev));
    }
    __syncthreads();
  }
}

// ---------------- g accumulation (unnormalized) + denominator
__global__ void kaccum(const float* __restrict__ x, const float* __restrict__ Wl,
                       const int* __restrict__ batch,
                       const int* __restrict__ cnt, const int* __restrict__ list,
                       const float* __restrict__ eex, const unsigned* __restrict__ mexkey,
                       float* __restrict__ den, float* __restrict__ gacc){
  __shared__ float xs[256];
  int t = blockIdx.y;
  int c = threadIdx.x;
  int nc = min(cnt[t], CAP);
  for (int ci = blockIdx.x; ci < nc; ci += gridDim.x){
    int n = list[t*CAP + ci];
    xs[c] = x[(size_t)t*N_*256 + (size_t)n*256 + c];
    __syncthreads();
    const float* wp = Wl + t*65536 + c;
    float a0 = 0.f, a1 = 0.f;
    #pragma unroll 8
    for (int k = 0; k < 256; k += 2){
      a0 += xs[k]   * wp[k*256];
      a1 += xs[k+1] * wp[(k+1)*256];
    }
    int b = batch[t*N_ + n];
    float m = dec_f(mexkey[t*B_ + b]);
    float w = expf(eex[t*CAP + ci] - m);
    if (c == 0) atomicAdd(&den[t*B_ + b], w);
    atomicAdd(&gacc[t*131072 + b*256 + c], w * (a0 + a1));
    __syncthreads();
  }
}

// ---------------- finalize g: d_out gout = gacc/den + bl-weighted bias_out
__global__ void kgfinal(const float* __restrict__ gacc, const float* __restrict__ den,
                        const float* __restrict__ bl, const float* __restrict__ bout,
                        float* __restrict__ gout){
  int i = blockIdx.x*256 + threadIdx.x;
  if (i >= 393216) return;
  int t = i >> 17, b = (i >> 8) & 511, c = i & 255;
  float d = den[t*B_ + b];
  // sum over candidates of alpha*(xl) ; alpha sums to 1 -> + bl + bias_out
  float v = (d > 0.f) ? gacc[i]/d + bl[t*256+c] : 0.f;
  gout[i] = v + bout[t*256 + c];
}

// ---------------- head GEMM: out = [tanh](Aeff@W + bias [+ addeff]), dual-z,
// Aeff: 0=plain, 1=concat-gather(ga,gfin), 2=tanh(bn(A)); addeff: 0/1 plain/2 bn
__global__ __launch_bounds__(256)
void kgemm2(const float* __restrict__ A, const float* __restrict__ addsrc,
            const float* __restrict__ ga, const float* __restrict__ gfin,
            const float* __restrict__ bnsums, const float* __restrict__ bng,
            const float* __restrict__ bnb, float* __restrict__ stats,
            const float* __restrict__ W0, const float* __restrict__ bias0,
            float* __restrict__ out0, int tanh0,
            const float* __restrict__ W1, const float* __restrict__ bias1,
            float* __restrict__ out1, int tanh1,
            int M, int N, int K, int aMode, int addMode){
  __shared__ float As[32][17];
  __shared__ __align__(16) float Ws[16][64];
  __shared__ float bnsc[512], bnsh[512];
  __shared__ float reds[16][64], reds2[16][64];

  const float* W = W0; const float* bias = bias0; float* out = out0; int dotanh = tanh0;
  if (blockIdx.z){ W = W1; bias = bias1; out = out1; dotanh = tanh1; }

  int tid = threadIdx.x;
  int tx = tid & 15, ty = tid >> 4;
  int row0 = blockIdx.y * 32, col0 = blockIdx.x * 64;

  if (aMode == 2 || addMode == 2){
    #pragma unroll
    for (int q = 0; q < 2; q++){
      int k = q*256 + tid;
      float mu = bnsums[k] * (1.f/512.f);
      float var = bnsums[512+k] * (1.f/512.f) - mu*mu;
      float sc = bng[k] * __frsqrt_rn(var + EPSb);
      bnsc[k] = sc;
      bnsh[k] = bnb[k] - mu*sc;
    }
    __syncthreads();
  }

  float acc[2][4] = {};
  for (int k0 = 0; k0 < K; k0 += 16){
    #pragma unroll
    for (int q = 0; q < 2; q++){
      int idx = tid*2 + q;
      int r = idx >> 4, kk = idx & 15;
      int kg = k0 + kk;
      float v;
      if (aMode == 0)      v = A[(size_t)(row0+r)*K + kg];
      else if (aMode == 1) v = (kg < 64) ? ga[(row0+r)*64 + kg]
                               : gfin[((kg-64) >> 8)*131072 + (row0+r)*256 + ((kg-64)&255)];
      else                 v = tanhf(A[(row0+r)*512 + kg]*bnsc[kg] + bnsh[kg]);
      As[r][kk] = v;
    }
    {
      int kr = tid >> 4, cc = (tid & 15)*4;
      *(f32x4*)&Ws[kr][cc] = *(const f32x4*)&W[(size_t)(k0+kr)*N + col0 + cc];
    }
    __syncthreads();
    #pragma unroll
    for (int kk = 0; kk < 16; kk++){
      float a0 = As[ty][kk], a1 = As[ty+16][kk];
      f32x4 wv = *(const f32x4*)&Ws[kk][tx*4];
      #pragma unroll
      for (int j = 0; j < 4; j++){
        acc[0][j] += a0*wv[j];
        acc[1][j] += a1*wv[j];
      }
    }
    __syncthreads();
  }

  float vout[2][4];
  #pragma unroll
  for (int i2 = 0; i2 < 2; i2++){
    int row = row0 + ty + i2*16;
    #pragma unroll
    for (int j = 0; j < 4; j++){
      int col = col0 + tx*4 + j;
      float v = acc[i2][j] + bias[col];
      if (addMode == 1) v += addsrc[(size_t)row*N + col];
      else if (addMode == 2) v += tanhf(addsrc[row*512 + col]*bnsc[col] + bnsh[col]);
      if (dotanh) v = tanhf(v);
      out[(size_t)row*N + col] = v;
      vout[i2][j] = v;
    }
  }

  if (stats){
    #pragma unroll
    for (int j = 0; j < 4; j++){
      float s  = vout[0][j] + vout[1][j];
      float s2 = vout[0][j]*vout[0][j] + vout[1][j]*vout[1][j];
      reds[ty][tx*4+j]  = s;
      reds2[ty][tx*4+j] = s2;
    }
    __syncthreads();
    if (tid < 128){
      int col = tid & 63, which = tid >> 6;
      const float (*src)[64] = which ? reds2 : reds;
      float s = 0.f;
      #pragma unroll
      for (int r = 0; r < 16; r++) s += src[r][col];
      atomicAdd(&stats[which*512 + col0 + col], s);
    }
  }
}

extern "C" void kernel_launch(void* const* d_in, const int* in_sizes, int n_in,
                              void* d_out, int out_size, void* d_ws, size_t ws_size,
                              hipStream_t stream){
  const float* x    = (const float*)d_in[0];
  const float* ga   = (const float*)d_in[1];
  const float* Wl   = (const float*)d_in[2];
  const float* bl   = (const float*)d_in[3];
  const float* Wr   = (const float*)d_in[4];
  const float* br   = (const float*)d_in[5];
  const float* att  = (const float*)d_in[6];
  const float* bout = (const float*)d_in[7];
  const float* gtok = (const float*)d_in[8];
  const float* m1pw = (const float*)d_in[9];
  const float* m1pb = (const float*)d_in[10];
  const float* m1w1 = (const float*)d_in[11];
  const float* m1b1 = (const float*)d_in[12];
  const float* m1w2 = (const float*)d_in[13];
  const float* m1b2 = (const float*)d_in[14];
  const float* bn1g = (const float*)d_in[15];
  const float* bn1b = (const float*)d_in[16];
  const float* m2w1 = (const float*)d_in[17];
  const float* m2b1 = (const float*)d_in[18];
  const float* m2w2 = (const float*)d_in[19];
  const float* m2b2 = (const float*)d_in[20];
  const float* bn2g = (const float*)d_in[21];
  const float* bn2b = (const float*)d_in[22];
  const float* m3pw = (const float*)d_in[23];
  const float* m3pb = (const float*)d_in[24];
  const float* m3w1 = (const float*)d_in[25];
  const float* m3b1 = (const float*)d_in[26];
  const float* m3w2 = (const float*)d_in[27];
  const float* m3b2 = (const float*)d_in[28];
  const int*   batch= (const int*)d_in[29];

  float* gout = (float*)d_out;              // [3][512][256]
  float* hout = (float*)d_out + 393216;     // [512][256]

  char* w = (char*)d_ws;
  __hip_bfloat16* wlt = (__hip_bfloat16*)(w + 0);   // 393216 B
  float*    cvec = (float*)(w + 393216);
  float*    ebuf = (float*)(w + 396288);
  int*      list = (int*)(w + 2796288);
  float*    eex  = (float*)(w + 3582720);
  // zero region start (399888 floats):
  float*    gacc = (float*)(w + 4369152);
  float*    den  = (float*)(w + 5942016);
  unsigned* mkey = (unsigned*)(w + 5948160);
  unsigned* mexkey=(unsigned*)(w + 5954304);
  float*    bns  = (float*)(w + 5960448);           // bns1[1024], bns2[1024]
  int*      cnt  = (int*)(w + 5968640);
  float*    T1   = (float*)(w + 5968704);
  float*    P1   = (float*)(w + 7017280);
  float*    Hm   = (float*)(w + 8065856);
  float*    T2   = (float*)(w + 9114432);
  float*    H2   = (float*)(w + 10163008);
  float*    T3   = (float*)(w + 11211584);
  float*    P3   = (float*)(w + 11735872);

  kprep<<<435, 256, 0, stream>>>(Wl, wlt, Wr, bl, br, gtok, cvec, gacc);
  k1<<<dim3(625, 3), 512, 0, stream>>>(x, wlt, cvec, att, batch, ebuf, mkey);
  kselect<<<dim3(782, 3), 256, 0, stream>>>(ebuf, batch, mkey, cnt, list);
  kexact<<<dim3(256, 3), 256, 0, stream>>>(x, Wl, cvec, att, batch, cnt, list, eex, mexkey);
  kaccum<<<dim3(256, 3), 256, 0, stream>>>(x, Wl, batch, cnt, list, eex, mexkey, den, gacc);
  kgfinal<<<1536, 256, 0, stream>>>(gacc, den, bl, bout, gout);
  // stage 1: T1 = tanh(h0@m1w1+b1), P1 = h0@m1pw+pb  (gather A)
  kgemm2<<<dim3(8,16,2), 256, 0, stream>>>(nullptr, nullptr, ga, gout,
      nullptr, nullptr, nullptr, nullptr,
      m1w1, m1b1, T1, 1, m1pw, m1pb, P1, 0, 512, 512, 832, 1, 0);
  // Hm = T1@m1w2 + b2 + P1, bn1 stats fused
  kgemm2<<<dim3(8,16,1), 256, 0, stream>>>(T1, P1, nullptr, nullptr,
      nullptr, nullptr, nullptr, bns,
      m1w2, m1b2, Hm, 0, nullptr, nullptr, nullptr, 0, 512, 512, 512, 0, 1);
  // T2 = tanh( tanh(bn1(Hm)) @ m2w1 + b1 )
  kgemm2<<<dim3(8,16,1), 256, 0, stream>>>(Hm, nullptr, nullptr, nullptr,
      bns, bn1g, bn1b, nullptr,
      m2w1, m2b1, T2, 1, nullptr, nullptr, nullptr, 0, 512, 512, 512, 2, 0);
  // H2 = T2@m2w2 + b2 + tanh(bn1(Hm)), bn2 stats fused
  kgemm2<<<dim3(8,16,1), 256, 0, stream>>>(T2, Hm, nullptr, nullptr,
      bns, bn1g, bn1b, bns + 1024,
      m2w2, m2b2, H2, 0, nullptr, nullptr, nullptr, 0, 512, 512, 512, 0, 2);
  // stage 3: A = tanh(bn2(H2)); T3 = tanh(A@m3w1+b1), P3 = A@m3pw+pb
  kgemm2<<<dim3(4,16,2), 256, 0, stream>>>(H2, nullptr, nullptr, nullptr,
      bns + 1024, bn2g, bn2b, nullptr,
      m3w1, m3b1, T3, 1, m3pw, m3pb, P3, 0, 512, 256, 512, 2, 0);
  // hout = T3@m3w2 + b2 + P3
  kgemm2<<<dim3(4,16,1), 256, 0, stream>>>(T3, P3, nullptr, nullptr,
      nullptr, nullptr, nullptr, nullptr,
      m3w2, m3b2, hout, 0, nullptr, nullptr, nullptr, 0, 512, 256, 256, 0, 1);
}

// Round 4
// 578.848 us; speedup vs baseline: 1.1107x; 1.1107x over previous
//
#include <hip/hip_runtime.h>
#include <hip/hip_bf16.h>

typedef __bf16 bf16x8 __attribute__((ext_vector_type(8)));
typedef float  f32x4  __attribute__((ext_vector_type(4)));

#define T_   3
#define N_   200000
#define C_   256
#define B_   512
#define CAP  65536
#define EPSb 1e-5f
#define NTILES 9375   // 3 * 200000/64

__device__ __forceinline__ unsigned enc_f(float f){
  unsigned u = __float_as_uint(f);
  return (u & 0x80000000u) ? ~u : (u | 0x80000000u);
}
__device__ __forceinline__ float dec_f(unsigned k){
  unsigned u = (k & 0x80000000u) ? (k ^ 0x80000000u) : ~k;
  return __uint_as_float(u);
}

// raw barrier WITHOUT vmcnt drain (lets prefetch global loads stay in flight)
__device__ __forceinline__ void barrier_nodrain(){
  __builtin_amdgcn_sched_barrier(0);
  asm volatile("s_waitcnt lgkmcnt(0)" ::: "memory");
  __builtin_amdgcn_s_barrier();
  __builtin_amdgcn_sched_barrier(0);
}

// ---------------- prep: Wl transpose->bf16, cvec, zero-fill (one kernel)
__global__ void kprep(const float* __restrict__ Wl, __hip_bfloat16* __restrict__ wlt,
                      const float* __restrict__ Wr, const float* __restrict__ bl,
                      const float* __restrict__ br, const float* __restrict__ gtok,
                      float* __restrict__ cvec, float* __restrict__ zr){
  __shared__ float tile[64][65];
  __shared__ float gt[256];
  int blk = blockIdx.x, tid = threadIdx.x;
  if (blk < 48){
    int t = blk / 16, rem = blk % 16;
    int k0 = (rem >> 2)*64, c0 = (rem & 3)*64;
    int lc = tid & 63, lr0 = tid >> 6;
    #pragma unroll
    for (int q = 0; q < 16; q++){
      int lr = lr0*16 + q;
      tile[lr][lc] = Wl[t*65536 + (k0+lr)*256 + (c0+lc)];
    }
    __syncthreads();
    #pragma unroll
    for (int q = 0; q < 16; q++){
      int lr = lr0*16 + q;
      wlt[t*65536 + (c0+lr)*256 + (k0+lc)] = __float2bfloat16(tile[lc][lr]);
    }
  } else if (blk < 51){
    int t = blk - 48, c = tid;
    gt[tid] = gtok[t*256 + tid];
    __syncthreads();
    const float* wr = Wr + t*65536 + c;
    float a0=0.f,a1=0.f,a2=0.f,a3=0.f;
    #pragma unroll 2
    for (int k = 0; k < 256; k += 4){
      a0 += gt[k]  *wr[k*256];
      a1 += gt[k+1]*wr[(k+1)*256];
      a2 += gt[k+2]*wr[(k+2)*256];
      a3 += gt[k+3]*wr[(k+3)*256];
    }
    cvec[t*256 + c] = a0+a1+a2+a3 + bl[t*256+c] + br[t*256+c];
  } else {
    // zero region: gacc(393216) + den(1536) + mkey(1536) + bns(2048) + cnt(16)
    for (int i = (blk-51)*256 + tid; i < 398352; i += (gridDim.x-51)*256) zr[i] = 0.f;
  }
}

// ---------------- big pass (persistent): e_approx = att . lrelu(x@Wl + cvec)
__global__ __launch_bounds__(512, 2)
void k1(const float* __restrict__ x, const __hip_bfloat16* __restrict__ wlt,
        const float* __restrict__ cvec, const float* __restrict__ att,
        const int* __restrict__ batch, float* __restrict__ e_out,
        unsigned* __restrict__ mkey){
  __shared__ __align__(16) __hip_bfloat16 Abuf[64][256];
  __shared__ float elds[4][64];
  const int tid = threadIdx.x;
  const int w = tid >> 6, l = tid & 63;
  const int wcol = w & 3, wrow = w >> 2;
  const int l15 = l & 15, l4 = l >> 4;
  const int srow = tid >> 3;
  const int sc   = tid & 7;
  const int sx   = srow & 7;

  bf16x8 bfr[8][4];
  float cv[4], at[4];
  int cur_t = -1;

  int gt = blockIdx.x;
  f32x4 rg[8];
  {
    int t = gt / 3125, tile = gt % 3125;
    const float* xrow = x + (size_t)t*N_*256 + (size_t)(tile*64 + srow)*256;
    #pragma unroll
    for (int q = 0; q < 4; q++){
      int cs = (q*8 + sc) ^ sx;
      rg[2*q]   = *(const f32x4*)(xrow + cs*8);
      rg[2*q+1] = *(const f32x4*)(xrow + cs*8 + 4);
    }
  }

  for (; gt < NTILES; gt += 512){
    const int t = gt / 3125, tile = gt % 3125;
    if (t != cur_t){
      cur_t = t;
      const __hip_bfloat16* WT = wlt + t*65536;
      #pragma unroll
      for (int fn = 0; fn < 4; fn++){
        int col = wcol*64 + fn*16 + l15;
        cv[fn] = cvec[t*256 + col];
        at[fn] = att[t*256 + col];
        #pragma unroll
        for (int ks = 0; ks < 8; ks++)
          bfr[ks][fn] = *(const bf16x8*)(WT + col*256 + ks*32 + l4*8);
      }
    }
    // stage rg -> LDS (swizzled slots)
    #pragma unroll
    for (int q = 0; q < 4; q++){
      bf16x8 v;
      #pragma unroll
      for (int j = 0; j < 4; j++){ v[j] = (__bf16)rg[2*q][j]; v[4+j] = (__bf16)rg[2*q+1][j]; }
      *(bf16x8*)(&Abuf[srow][(q*8 + sc)*8]) = v;
    }
    // prefetch next persistent iteration (stays in flight across barrier)
    int gn = gt + 512;
    if (gn < NTILES){
      int tn = gn / 3125, tilen = gn % 3125;
      const float* xrow = x + (size_t)tn*N_*256 + (size_t)(tilen*64 + srow)*256;
      #pragma unroll
      for (int q = 0; q < 4; q++){
        int cs = (q*8 + sc) ^ sx;
        rg[2*q]   = *(const f32x4*)(xrow + cs*8);
        rg[2*q+1] = *(const f32x4*)(xrow + cs*8 + 4);
      }
    }
    barrier_nodrain();

    f32x4 acc[2][4];
    #pragma unroll
    for (int fm = 0; fm < 2; fm++)
      #pragma unroll
      for (int fn = 0; fn < 4; fn++)
        acc[fm][fn] = (f32x4){0.f,0.f,0.f,0.f};

    #pragma unroll
    for (int ks = 0; ks < 8; ks++){
      bf16x8 a8[2];
      #pragma unroll
      for (int fm = 0; fm < 2; fm++){
        int row  = wrow*32 + fm*16 + l15;
        int slot = (ks*4 + l4) ^ (row & 7);
        a8[fm] = *(const bf16x8*)(&Abuf[row][slot*8]);
      }
      #pragma unroll
      for (int fm = 0; fm < 2; fm++)
        #pragma unroll
        for (int fn = 0; fn < 4; fn++)
          acc[fm][fn] = __builtin_amdgcn_mfma_f32_16x16x32_bf16(a8[fm], bfr[ks][fn], acc[fm][fn], 0, 0, 0);
    }

    #pragma unroll
    for (int fm = 0; fm < 2; fm++){
      #pragma unroll
      for (int r = 0; r < 4; r++){
        float v = 0.f;
        #pragma unroll
        for (int fn = 0; fn < 4; fn++){
          float xv = acc[fm][fn][r] + cv[fn];
          xv = (xv > 0.f) ? xv : 0.2f*xv;
          v += xv * at[fn];
        }
        v += __shfl_xor(v, 1);
        v += __shfl_xor(v, 2);
        v += __shfl_xor(v, 4);
        v += __shfl_xor(v, 8);
        if (l15 == 0) elds[wcol][wrow*32 + fm*16 + l4*4 + r] = v;
      }
    }
    barrier_nodrain();

    if (tid < 64){
      float ef = elds[0][tid] + elds[1][tid] + elds[2][tid] + elds[3][tid];
      int n = tile*64 + tid;
      e_out[t*N_ + n] = ef;
      int b = batch[t*N_ + n];
      float m = ef;
      #pragma unroll
      for (int off = 1; off < 64; off <<= 1){
        float up = __shfl_up(m, off);
        int   bu = __shfl_up(b, off);
        if (tid >= off && bu == b) m = fmaxf(m, up);
      }
      int bnx = __shfl_down(b, 1);
      if (tid == 63 || b != bnx) atomicMax(&mkey[t*B_ + b], enc_f(m));
    }
  }
}

// ---------------- candidate selection: e >= segmax - 30
__global__ void kselect(const float* __restrict__ e, const int* __restrict__ batch,
                        const unsigned* __restrict__ mkey, int* cnt, int* list){
  int t = blockIdx.y;
  int n = blockIdx.x*256 + threadIdx.x;
  if (n >= N_) return;
  float ev = e[t*N_ + n];
  int b = batch[t*N_ + n];
  float m = dec_f(mkey[t*B_ + b]);
  if (ev >= m - 30.0f){
    int pos = atomicAdd(&cnt[t], 1);
    if (pos < CAP) list[t*CAP + pos] = n;
  }
}

// ---------------- fused candidate pass: exact xl + exact e + den + gacc
// (softmax shift uses approx max mkey: alpha = exp(e-m)/sum exp(e-m) is
//  shift-invariant, so any consistent per-segment m is exact)
__global__ void kcand(const float* __restrict__ x, const float* __restrict__ Wl,
                      const float* __restrict__ cvec, const float* __restrict__ att,
                      const int* __restrict__ batch, const int* __restrict__ cnt,
                      const int* __restrict__ list, const unsigned* __restrict__ mkey,
                      float* __restrict__ den, float* __restrict__ gacc){
  __shared__ float xs[256];
  __shared__ float red[4];
  __shared__ float ebc;
  int t = blockIdx.y;
  int c = threadIdx.x;
  int nc = min(cnt[t], CAP);
  for (int ci = blockIdx.x; ci < nc; ci += gridDim.x){
    int n = list[t*CAP + ci];
    xs[c] = x[(size_t)t*N_*256 + (size_t)n*256 + c];
    __syncthreads();
    const float* wp = Wl + t*65536 + c;
    float a0 = 0.f, a1 = 0.f;
    #pragma unroll 8
    for (int k = 0; k < 256; k += 2){
      a0 += xs[k]   * wp[k*256];
      a1 += xs[k+1] * wp[(k+1)*256];
    }
    float xl = a0 + a1;
    float xv = xl + cvec[t*256 + c];
    xv = (xv > 0.f) ? xv : 0.2f*xv;
    float term = xv * att[t*256 + c];
    #pragma unroll
    for (int off = 1; off < 64; off <<= 1) term += __shfl_xor(term, off);
    if ((c & 63) == 0) red[c >> 6] = term;
    __syncthreads();
    if (c == 0) ebc = red[0] + red[1] + red[2] + red[3];
    __syncthreads();
    int b = batch[t*N_ + n];
    float m = dec_f(mkey[t*B_ + b]);
    float wv = expf(ebc - m);
    if (c == 0) atomicAdd(&den[t*B_ + b], wv);
    atomicAdd(&gacc[t*131072 + b*256 + c], wv * xl);
    __syncthreads();
  }
}

// ---------------- finalize g: gout = gacc/den + bl + bias_out
__global__ void kgfinal(const float* __restrict__ gacc, const float* __restrict__ den,
                        const float* __restrict__ bl, const float* __restrict__ bout,
                        float* __restrict__ gout){
  int i = blockIdx.x*256 + threadIdx.x;
  if (i >= 393216) return;
  int t = i >> 17, b = (i >> 8) & 511, c = i & 255;
  float d = den[t*B_ + b];
  float v = (d > 0.f) ? gacc[i]/d + bl[t*256+c] : 0.f;
  gout[i] = v + bout[t*256 + c];
}

// ---------------- head GEMM: out = [tanh](Aeff@W + bias [+ addeff]), dual-z,
// Aeff: 0=plain, 1=concat-gather(ga,gfin), 2=tanh(bn(A)); addeff: 0/1 plain/2 bn
__global__ __launch_bounds__(256)
void kgemm2(const float* __restrict__ A, const float* __restrict__ addsrc,
            const float* __restrict__ ga, const float* __restrict__ gfin,
            const float* __restrict__ bnsums, const float* __restrict__ bng,
            const float* __restrict__ bnb, float* __restrict__ stats,
            const float* __restrict__ W0, const float* __restrict__ bias0,
            float* __restrict__ out0, int tanh0,
            const float* __restrict__ W1, const float* __restrict__ bias1,
            float* __restrict__ out1, int tanh1,
            int M, int N, int K, int aMode, int addMode){
  __shared__ float As[32][17];
  __shared__ __align__(16) float Ws[16][64];
  __shared__ float bnsc[512], bnsh[512];
  __shared__ float reds[16][64], reds2[16][64];

  const float* W = W0; const float* bias = bias0; float* out = out0; int dotanh = tanh0;
  if (blockIdx.z){ W = W1; bias = bias1; out = out1; dotanh = tanh1; }

  int tid = threadIdx.x;
  int tx = tid & 15, ty = tid >> 4;
  int row0 = blockIdx.y * 32, col0 = blockIdx.x * 64;

  if (aMode == 2 || addMode == 2){
    #pragma unroll
    for (int q = 0; q < 2; q++){
      int k = q*256 + tid;
      float mu = bnsums[k] * (1.f/512.f);
      float var = bnsums[512+k] * (1.f/512.f) - mu*mu;
      float sc = bng[k] * __frsqrt_rn(var + EPSb);
      bnsc[k] = sc;
      bnsh[k] = bnb[k] - mu*sc;
    }
    __syncthreads();
  }

  float acc[2][4] = {};
  for (int k0 = 0; k0 < K; k0 += 16){
    #pragma unroll
    for (int q = 0; q < 2; q++){
      int idx = tid*2 + q;
      int r = idx >> 4, kk = idx & 15;
      int kg = k0 + kk;
      float v;
      if (aMode == 0)      v = A[(size_t)(row0+r)*K + kg];
      else if (aMode == 1) v = (kg < 64) ? ga[(row0+r)*64 + kg]
                               : gfin[((kg-64) >> 8)*131072 + (row0+r)*256 + ((kg-64)&255)];
      else                 v = tanhf(A[(row0+r)*512 + kg]*bnsc[kg] + bnsh[kg]);
      As[r][kk] = v;
    }
    {
      int kr = tid >> 4, cc = (tid & 15)*4;
      *(f32x4*)&Ws[kr][cc] = *(const f32x4*)&W[(size_t)(k0+kr)*N + col0 + cc];
    }
    __syncthreads();
    #pragma unroll
    for (int kk = 0; kk < 16; kk++){
      float a0 = As[ty][kk], a1 = As[ty+16][kk];
      f32x4 wv = *(const f32x4*)&Ws[kk][tx*4];
      #pragma unroll
      for (int j = 0; j < 4; j++){
        acc[0][j] += a0*wv[j];
        acc[1][j] += a1*wv[j];
      }
    }
    __syncthreads();
  }

  float vout[2][4];
  #pragma unroll
  for (int i2 = 0; i2 < 2; i2++){
    int row = row0 + ty + i2*16;
    #pragma unroll
    for (int j = 0; j < 4; j++){
      int col = col0 + tx*4 + j;
      float v = acc[i2][j] + bias[col];
      if (addMode == 1) v += addsrc[(size_t)row*N + col];
      else if (addMode == 2) v += tanhf(addsrc[row*512 + col]*bnsc[col] + bnsh[col]);
      if (dotanh) v = tanhf(v);
      out[(size_t)row*N + col] = v;
      vout[i2][j] = v;
    }
  }

  if (stats){
    #pragma unroll
    for (int j = 0; j < 4; j++){
      float s  = vout[0][j] + vout[1][j];
      float s2 = vout[0][j]*vout[0][j] + vout[1][j]*vout[1][j];
      reds[ty][tx*4+j]  = s;
      reds2[ty][tx*4+j] = s2;
    }
    __syncthreads();
    if (tid < 128){
      int col = tid & 63, which = tid >> 6;
      const float (*src)[64] = which ? reds2 : reds;
      float s = 0.f;
      #pragma unroll
      for (int r = 0; r < 16; r++) s += src[r][col];
      atomicAdd(&stats[which*512 + col0 + col], s);
    }
  }
}

extern "C" void kernel_launch(void* const* d_in, const int* in_sizes, int n_in,
                              void* d_out, int out_size, void* d_ws, size_t ws_size,
                              hipStream_t stream){
  const float* x    = (const float*)d_in[0];
  const float* ga   = (const float*)d_in[1];
  const float* Wl   = (const float*)d_in[2];
  const float* bl   = (const float*)d_in[3];
  const float* Wr   = (const float*)d_in[4];
  const float* br   = (const float*)d_in[5];
  const float* att  = (const float*)d_in[6];
  const float* bout = (const float*)d_in[7];
  const float* gtok = (const float*)d_in[8];
  const float* m1pw = (const float*)d_in[9];
  const float* m1pb = (const float*)d_in[10];
  const float* m1w1 = (const float*)d_in[11];
  const float* m1b1 = (const float*)d_in[12];
  const float* m1w2 = (const float*)d_in[13];
  const float* m1b2 = (const float*)d_in[14];
  const float* bn1g = (const float*)d_in[15];
  const float* bn1b = (const float*)d_in[16];
  const float* m2w1 = (const float*)d_in[17];
  const float* m2b1 = (const float*)d_in[18];
  const float* m2w2 = (const float*)d_in[19];
  const float* m2b2 = (const float*)d_in[20];
  const float* bn2g = (const float*)d_in[21];
  const float* bn2b = (const float*)d_in[22];
  const float* m3pw = (const float*)d_in[23];
  const float* m3pb = (const float*)d_in[24];
  const float* m3w1 = (const float*)d_in[25];
  const float* m3b1 = (const float*)d_in[26];
  const float* m3w2 = (const float*)d_in[27];
  const float* m3b2 = (const float*)d_in[28];
  const int*   batch= (const int*)d_in[29];

  float* gout = (float*)d_out;              // [3][512][256]
  float* hout = (float*)d_out + 393216;     // [512][256]

  char* w = (char*)d_ws;
  __hip_bfloat16* wlt = (__hip_bfloat16*)(w + 0);   // 393216 B
  float*    cvec = (float*)(w + 393216);            // 3072 B
  float*    ebuf = (float*)(w + 396288);            // 2400000 B
  int*      list = (int*)(w + 2796288);             // 786432 B
  // zero region (398352 floats):
  float*    gacc = (float*)(w + 3582720);           // 1572864 B
  float*    den  = (float*)(w + 5155584);           // 6144 B
  unsigned* mkey = (unsigned*)(w + 5161728);        // 6144 B
  float*    bns  = (float*)(w + 5167872);           // 8192 B
  int*      cnt  = (int*)(w + 5176064);             // 64 B
  // head temps:
  float*    T1   = (float*)(w + 5176128);
  float*    P1   = (float*)(w + 6224704);
  float*    Hm   = (float*)(w + 7273280);
  float*    T2   = (float*)(w + 8321856);
  float*    H2   = (float*)(w + 9370432);
  float*    T3   = (float*)(w + 10419008);
  float*    P3   = (float*)(w + 10943296);

  kprep<<<435, 256, 0, stream>>>(Wl, wlt, Wr, bl, br, gtok, cvec, gacc);
  k1<<<512, 512, 0, stream>>>(x, wlt, cvec, att, batch, ebuf, mkey);
  kselect<<<dim3(782, 3), 256, 0, stream>>>(ebuf, batch, mkey, cnt, list);
  kcand<<<dim3(256, 3), 256, 0, stream>>>(x, Wl, cvec, att, batch, cnt, list, mkey, den, gacc);
  kgfinal<<<1536, 256, 0, stream>>>(gacc, den, bl, bout, gout);
  // stage 1: T1 = tanh(h0@m1w1+b1), P1 = h0@m1pw+pb  (gather A)
  kgemm2<<<dim3(8,16,2), 256, 0, stream>>>(nullptr, nullptr, ga, gout,
      nullptr, nullptr, nullptr, nullptr,
      m1w1, m1b1, T1, 1, m1pw, m1pb, P1, 0, 512, 512, 832, 1, 0);
  // Hm = T1@m1w2 + b2 + P1, bn1 stats fused
  kgemm2<<<dim3(8,16,1), 256, 0, stream>>>(T1, P1, nullptr, nullptr,
      nullptr, nullptr, nullptr, bns,
      m1w2, m1b2, Hm, 0, nullptr, nullptr, nullptr, 0, 512, 512, 512, 0, 1);
  // T2 = tanh( tanh(bn1(Hm)) @ m2w1 + b1 )
  kgemm2<<<dim3(8,16,1), 256, 0, stream>>>(Hm, nullptr, nullptr, nullptr,
      bns, bn1g, bn1b, nullptr,
      m2w1, m2b1, T2, 1, nullptr, nullptr, nullptr, 0, 512, 512, 512, 2, 0);
  // H2 = T2@m2w2 + b2 + tanh(bn1(Hm)), bn2 stats fused
  kgemm2<<<dim3(8,16,1), 256, 0, stream>>>(T2, Hm, nullptr, nullptr,
      bns, bn1g, bn1b, bns + 1024,
      m2w2, m2b2, H2, 0, nullptr, nullptr, nullptr, 0, 512, 512, 512, 0, 2);
  // stage 3: A = tanh(bn2(H2)); T3 = tanh(A@m3w1+b1), P3 = A@m3pw+pb
  kgemm2<<<dim3(4,16,2), 256, 0, stream>>>(H2, nullptr, nullptr, nullptr,
      bns + 1024, bn2g, bn2b, nullptr,
      m3w1, m3b1, T3, 1, m3pw, m3pb, P3, 0, 512, 256, 512, 2, 0);
  // hout = T3@m3w2 + b2 + P3
  kgemm2<<<dim3(4,16,1), 256, 0, stream>>>(T3, P3, nullptr, nullptr,
      nullptr, nullptr, nullptr, nullptr,
      m3w2, m3b2, hout, 0, nullptr, nullptr, nullptr, 0, 512, 256, 256, 0, 1);
}